// Round 1
// 318.442 us; speedup vs baseline: 1.0121x; 1.0121x over previous
//
#include <hip/hip_runtime.h>
#include <math.h>

// HighDimAELoss: associative-embedding push/pull loss.
// tags [B,D,R,R] fp32; joints [B,M,J,2] int32 (flat idx, visibility).
// out: push[B] ++ pull[B] (fp32).
//
// Two-kernel structure:
//  K1: one thread per (b,m,j,d) scattered gather -> ws (uses all 256 CUs for
//      max memory-level parallelism). NEW: visibility-gated — invalid joints
//      (~50% of them) never touch tags and never write ws, halving the
//      scattered-line traffic that dominates this kernel.
//  K2: one block per image; all reductions from the L2-resident ws copy.
//      NEW: phase 1 never reads ws for invalid joints (ws is poisoned between
//      iterations — reading it for masked joints would inject NaN via 0*poison),
//      zeroing t_s instead, which also lets phase 2 drop the valid multiply.

constexpr int B_ = 16, M_ = 30, J_ = 17, D_ = 17, R_ = 512;
constexpr int TOT_ = B_ * M_ * J_ * D_;   // 138720 gather slots

__global__ __launch_bounds__(256) void ae_gather_kernel(
    const float* __restrict__ tags, const int* __restrict__ joints,
    float* __restrict__ t_ws) {
  const int i = blockIdx.x * blockDim.x + threadIdx.x;
  if (i >= TOT_) return;
  const int d = i % D_;
  const int bmj = i / D_;                 // b*M*J + m*J + j
  const int vis = joints[2 * bmj + 1];    // broadcast across the 17 d-lanes
  if (vis <= 0) return;                   // dead joint: skip load AND store
  const int b = bmj / (M_ * J_);
  int off = joints[2 * bmj];
  off %= (R_ * R_);
  if (off < 0) off += R_ * R_;
  const int x = off % R_;                 // first spatial axis (torch convention)
  const int y = off / R_;
  t_ws[i] = tags[(((size_t)b * D_ + d) * R_ + x) * R_ + y];
}

__global__ __launch_bounds__(512) void ae_reduce_kernel(
    const float* __restrict__ t_ws, const int* __restrict__ joints,
    float* __restrict__ out) {
  const int b = blockIdx.x;
  const int tid = threadIdx.x;
  const int nthr = blockDim.x;

  __shared__ float t_s[M_][J_][D_];     // gathered tag vectors  (34.7 KB)
  __shared__ float valid_s[M_][J_];
  __shared__ float cnt_s[M_];           // #valid joints per person
  __shared__ float pullnum_s[M_];       // sum_j sq*valid per person
  __shared__ float mean_s[M_][D_];      // per-person mean tag
  __shared__ float pv_s[M_];            // person_valid
  __shared__ float scal_s[2];           // n_tags, pull
  __shared__ float wavered[8];

  if (tid < M_) { cnt_s[tid] = 0.f; pullnum_s[tid] = 0.f; }
  __syncthreads();

  const int* jb = joints + b * M_ * J_ * 2;
  const float* tb = t_ws + (size_t)b * M_ * J_ * D_;

  // Phase 1: one thread per (m,j). Only valid joints read ws (poison-safe);
  // sq via sum_{d,e}(t_d-t_e)^2 = 2*(D*sum(t^2) - (sum t)^2)
  for (int mj = tid; mj < M_ * J_; mj += nthr) {
    const int m = mj / J_;
    const int j = mj - m * J_;
    const int vis = jb[2 * mj + 1];
    if (vis > 0) {
      const float* p = tb + (size_t)mj * D_;
      float s1 = 0.f, s2 = 0.f;
#pragma unroll
      for (int d = 0; d < D_; ++d) {
        const float v = p[d];
        t_s[m][j][d] = v;
        s1 += v;
        s2 += v * v;
      }
      valid_s[m][j] = 1.f;
      const float sq = 2.f * ((float)D_ * s2 - s1 * s1);
      atomicAdd(&pullnum_s[m], sq);
      atomicAdd(&cnt_s[m], 1.f);
    } else {
#pragma unroll
      for (int d = 0; d < D_; ++d) t_s[m][j][d] = 0.f;
      valid_s[m][j] = 0.f;
    }
  }
  __syncthreads();

  // Phase 2: mean_tag per (m,d) — invalid joints hold exact 0s in t_s,
  // so no valid multiply needed.
  for (int i = tid; i < M_ * D_; i += nthr) {
    const int m = i / D_;
    const int d = i - m * D_;
    float s = 0.f;
#pragma unroll
    for (int j = 0; j < J_; ++j) s += t_s[m][j][d];
    mean_s[m][d] = s / fmaxf(cnt_s[m], 1.f);
  }
  if (tid < M_) pv_s[tid] = (cnt_s[tid] > 0.f) ? 1.f : 0.f;
  __syncthreads();

  // Phase 3: n_tags + pull (serial over 30 — negligible)
  if (tid == 0) {
    float nt = 0.f, pull = 0.f;
    for (int m = 0; m < M_; ++m) {
      nt += pv_s[m];
      const float safe = fmaxf(cnt_s[m], 1.f);
      pull += pv_s[m] * pullnum_s[m] / ((float)(D_ * D_) * safe);
    }
    scal_s[0] = nt;
    scal_s[1] = pull / fmaxf(nt, 1.f);
  }
  __syncthreads();

  // Phase 4: push over M*M person pairs (diagonal included, as in ref)
  float acc = 0.f;
  for (int mn = tid; mn < M_ * M_; mn += nthr) {
    const int m = mn / M_;
    const int n = mn - m * M_;
    const float w = pv_s[m] * pv_s[n];
    if (w > 0.f) {
      float s = 0.f;
#pragma unroll
      for (int d = 0; d < D_; ++d) {
        const float pd = mean_s[m][d] - mean_s[n][d];
        s += expf(-pd * pd);
      }
      acc += s * (1.f / (float)D_) * w;
    }
  }
  // block reduction: wave64 shuffle then cross-wave via LDS
#pragma unroll
  for (int o = 32; o > 0; o >>= 1) acc += __shfl_down(acc, o, 64);
  const int wave = tid >> 6;
  const int lane = tid & 63;
  if (lane == 0) wavered[wave] = acc;
  __syncthreads();
  if (tid == 0) {
    float tot = 0.f;
    for (int w = 0; w < (nthr >> 6); ++w) tot += wavered[w];
    const float nt = scal_s[0];
    const float safe_nt = fmaxf(nt, 1.f);
    const float push = (nt >= 2.f) ? tot / (safe_nt * safe_nt) : 0.f;
    out[b] = push;            // push[b]
    out[B_ + b] = scal_s[1];  // pull[b]
  }
}

extern "C" void kernel_launch(void* const* d_in, const int* in_sizes, int n_in,
                              void* d_out, int out_size, void* d_ws, size_t ws_size,
                              hipStream_t stream) {
  const float* tags = (const float*)d_in[0];
  const int* joints = (const int*)d_in[1];
  float* out = (float*)d_out;
  float* t_ws = (float*)d_ws;   // B*M*J*D floats = 555 KB

  ae_gather_kernel<<<(TOT_ + 255) / 256, 256, 0, stream>>>(tags, joints, t_ws);
  ae_reduce_kernel<<<B_, 512, 0, stream>>>(t_ws, joints, out);
}